// Round 5
// baseline (1280.207 us; speedup 1.0000x reference)
//
#include <hip/hip_runtime.h>
#include <hip/hip_fp16.h>

static constexpr int ID   = 128;    // IN_DIM
static constexpr int ND   = 32;     // NET_DIM
static constexpr int NPB  = 128;    // nodes per dest bucket (lc fits 7 bits)
static constexpr int T    = 4;      // source tiles: tile = row >> 15
static constexpr int CPAD = 16;     // u32 per bin cursor (64B line)
static constexpr int EPB  = 16384;  // edges per k_place block
static constexpr int BINS_MAX = 3200;  // >= 782*4 = 3128

union H2U { __half2 h; unsigned u; float f; };
static __device__ __forceinline__ float pack2(float a, float b) {
    H2U z; z.h = __floats2half2_rn(a, b); return z.f;
}

// ---- fused counts: node in-degree + (bucket,tile) bin sizes ----
__global__ __launch_bounds__(256) void k_count2(const int* __restrict__ row,
                                                const int* __restrict__ col, int E,
                                                unsigned* __restrict__ cnt,
                                                unsigned* __restrict__ bincnt) {
    int e = blockIdx.x * 256 + threadIdx.x;
    if (e < E) {
        int c = col[e];
        atomicAdd(&cnt[c], 1u);
        atomicAdd(&bincnt[(c >> 7) * T + (row[e] >> 15)], 1u);
    }
}

// ---- dinv = rsqrt(deg+1) ----
__global__ __launch_bounds__(256) void k_dinv(const unsigned* __restrict__ cnt,
                                              float* __restrict__ dinv, int n) {
    int i = blockIdx.x * 256 + threadIdx.x;
    if (i < n) dinv[i] = rsqrtf((float)(cnt[i] + 1u));
}

// ---- exclusive scan of bin sizes (1 block, 4 elems/thread, nbins<=4096) ----
__global__ __launch_bounds__(1024) void k_scan2(const unsigned* __restrict__ bincnt, int nbins,
                                                unsigned* __restrict__ boff2,
                                                unsigned* __restrict__ bcur) {
    __shared__ unsigned s[1024];
    int t = threadIdx.x;
    unsigned v[4]; unsigned lsum = 0u;
#pragma unroll
    for (int j = 0; j < 4; ++j) {
        int i = t * 4 + j;
        v[j] = (i < nbins) ? bincnt[i] : 0u;
        lsum += v[j];
    }
    s[t] = lsum;
    __syncthreads();
    for (int d = 1; d < 1024; d <<= 1) {
        unsigned x = (t >= d) ? s[t - d] : 0u;
        __syncthreads();
        s[t] += x;
        __syncthreads();
    }
    unsigned run = s[t] - lsum;   // exclusive prefix of this thread's chunk
#pragma unroll
    for (int j = 0; j < 4; ++j) {
        int i = t * 4 + j;
        if (i < nbins) { boff2[i] = run; bcur[(size_t)i * CPAD] = run; }
        run += v[j];
    }
}

// ---- hs2 = fp16( dinv[i] * (x[i] @ W_gcn) ) ----
__global__ __launch_bounds__(256) void k_gemm(const float* __restrict__ x,
                                              const float* __restrict__ W,
                                              const float* __restrict__ dinv,
                                              __half* __restrict__ hs2, int n) {
    __shared__ float sW[ID * ND];        // 16 KB, [k][j]
    for (int i = threadIdx.x; i < ID * ND; i += 256) sW[i] = W[i];
    __syncthreads();
    int rowi = blockIdx.x * 256 + threadIdx.x;
    if (rowi >= n) return;
    float acc[ND];
#pragma unroll
    for (int j = 0; j < ND; ++j) acc[j] = 0.f;
    const float4* xr = reinterpret_cast<const float4*>(x + (size_t)rowi * ID);
    for (int k4 = 0; k4 < ID / 4; ++k4) {
        float4 v = xr[k4];
        const float* w0 = &sW[(k4 * 4 + 0) * ND];
        const float* w1 = &sW[(k4 * 4 + 1) * ND];
        const float* w2 = &sW[(k4 * 4 + 2) * ND];
        const float* w3 = &sW[(k4 * 4 + 3) * ND];
#pragma unroll
        for (int j = 0; j < ND; ++j)
            acc[j] += v.x * w0[j] + v.y * w1[j] + v.z * w2[j] + v.w * w3[j];
    }
    float di = dinv[rowi];
    float4* dst = reinterpret_cast<float4*>(hs2 + (size_t)rowi * ND);
#pragma unroll
    for (int q = 0; q < 4; ++q) {
        float4 f;
        f.x = pack2(di * acc[q * 8 + 0], di * acc[q * 8 + 1]);
        f.y = pack2(di * acc[q * 8 + 2], di * acc[q * 8 + 3]);
        f.z = pack2(di * acc[q * 8 + 4], di * acc[q * 8 + 5]);
        f.w = pack2(di * acc[q * 8 + 6], di * acc[q * 8 + 7]);
        dst[q] = f;
    }
}

// ---- 2-phase binning into (bucket,tile) bins; per-block chunk reserve ----
__global__ __launch_bounds__(1024) void k_place(const int* __restrict__ row,
                                                const int* __restrict__ col,
                                                unsigned* __restrict__ bcur,
                                                unsigned* __restrict__ packed,
                                                int E, int nbins) {
    __shared__ unsigned lcnt[BINS_MAX];
    int tid = threadIdx.x;
    for (int i = tid; i < nbins; i += 1024) lcnt[i] = 0u;
    __syncthreads();
    long base = (long)blockIdx.x * EPB;
#pragma unroll
    for (int i = 0; i < EPB / 1024; ++i) {
        long e = base + tid + (long)i * 1024;
        if (e < E) {
            int c = col[e];
            atomicAdd(&lcnt[(c >> 7) * T + (row[e] >> 15)], 1u);
        }
    }
    __syncthreads();
    for (int i = tid; i < nbins; i += 1024) {
        unsigned v = lcnt[i];
        lcnt[i] = v ? atomicAdd(&bcur[(size_t)i * CPAD], v) : 0u;  // becomes global cursor
    }
    __syncthreads();
#pragma unroll
    for (int i = 0; i < EPB / 1024; ++i) {
        long e = base + tid + (long)i * 1024;
        if (e < E) {
            int c = col[e];
            int r = row[e];
            int bin = (c >> 7) * T + (r >> 15);
            unsigned p = atomicAdd(&lcnt[bin], 1u);
            packed[p] = ((unsigned)(c & (NPB - 1)) << 17) | (unsigned)r;
        }
    }
}

// ---- fused tiled gather + LDS aggregate + finalize ----
// 512 thr = 8 waves; per wave-instr: 16 edges x 4 lanes x 16B fp16 (64B/edge).
// Tiles t=0..3 swept in lockstep by all (co-resident) blocks -> L2-hot slice.
__global__ __launch_bounds__(512) void k_agg(const unsigned* __restrict__ boff2,
                                             const unsigned* __restrict__ bincnt,
                                             const unsigned* __restrict__ packed,
                                             const __half* __restrict__ hs2,
                                             const float* __restrict__ dinv,
                                             const float* __restrict__ bg,
                                             const float* __restrict__ Wd,
                                             const float* __restrict__ bd,
                                             float* __restrict__ out, int n) {
    __shared__ float agg[NPB * ND];   // 16 KB, channel index swizzled by +lc
    __shared__ float sW[ND * ND];     // 4 KB
    __shared__ float sbg[ND];
    __shared__ float sbd[ND];
    int tid = threadIdx.x;
    for (int i = tid; i < NPB * ND; i += 512) agg[i] = 0.f;
    for (int i = tid; i < ND * ND; i += 512) sW[i] = Wd[i];
    if (tid < ND) { sbg[tid] = bg[tid]; sbd[tid] = bd[tid]; }
    __syncthreads();

    int b = blockIdx.x;
    int lane = tid & 63;
    int w    = tid >> 6;     // wave 0..7
    int sub  = lane >> 2;    // edge slot 0..15
    int l4   = lane & 3;     // 16B quad within fp16 row
    const float4* hs4 = reinterpret_cast<const float4*>(hs2);  // row = 4 x float4
    int cb = l4 * 8;

    for (int t = 0; t < T; ++t) {
        int bin = b * T + t;
        unsigned base = boff2[bin];
        unsigned m    = bincnt[bin];
        for (unsigned k = (unsigned)w * 32u; k < m; k += 256u) {
            unsigned i0 = k + (unsigned)sub;
            unsigned i1 = k + 16u + (unsigned)sub;
            bool g0 = i0 < m, g1 = i1 < m;
            unsigned e0 = g0 ? packed[base + i0] : 0u;
            unsigned e1 = g1 ? packed[base + i1] : 0u;
            float4 r0 = hs4[(size_t)(e0 & 0x1FFFFu) * 4 + l4];
            float4 r1 = hs4[(size_t)(e1 & 0x1FFFFu) * 4 + l4];
            if (g0) {
                int lc = (int)(e0 >> 17);
                const __half2* hp = reinterpret_cast<const __half2*>(&r0);
#pragma unroll
                for (int j = 0; j < 4; ++j) {
                    float2 f = __half22float2(hp[j]);
                    atomicAdd(&agg[lc * ND + ((cb + 2 * j     + lc) & 31)], f.x);
                    atomicAdd(&agg[lc * ND + ((cb + 2 * j + 1 + lc) & 31)], f.y);
                }
            }
            if (g1) {
                int lc = (int)(e1 >> 17);
                const __half2* hp = reinterpret_cast<const __half2*>(&r1);
#pragma unroll
                for (int j = 0; j < 4; ++j) {
                    float2 f = __half22float2(hp[j]);
                    atomicAdd(&agg[lc * ND + ((cb + 2 * j     + lc) & 31)], f.x);
                    atomicAdd(&agg[lc * ND + ((cb + 2 * j + 1 + lc) & 31)], f.y);
                }
            }
        }
    }
    __syncthreads();

    // finalize: 16 groups of 32 lanes, one node each
    int g32 = tid >> 5;
    int ch  = tid & 31;
    int nodebase = b * NPB;
    for (int lc = g32; lc < NPB; lc += 16) {
        int c = nodebase + lc;
        if (c < n) {
            float self = __half2float(hs2[(size_t)c * ND + ch]);
            float acc = agg[lc * ND + ((ch + lc) & 31)] + self;
            float g = fmaxf(dinv[c] * acc + sbg[ch], 0.f);
            float o = sbd[ch];
#pragma unroll
            for (int j = 0; j < ND; ++j) {
                float gj = __shfl(g, j, 32);
                o += gj * sW[j * ND + ch];
            }
            out[(size_t)c * ND + ch] = fmaxf(o, 0.f);
        }
    }
}

extern "C" void kernel_launch(void* const* d_in, const int* in_sizes, int n_in,
                              void* d_out, int out_size, void* d_ws, size_t ws_size,
                              hipStream_t stream) {
    const float* x  = (const float*)d_in[0];
    const int*   ei = (const int*)d_in[1];   // [2, E] flat: row then col
    const float* Wg = (const float*)d_in[2];
    const float* bg = (const float*)d_in[3];
    const float* Wd = (const float*)d_in[4];
    const float* bd = (const float*)d_in[5];
    float* out = (float*)d_out;

    const int n = in_sizes[0] / ID;        // 100000
    const int E = in_sizes[1] / 2;         // 3200000
    const int* erow = ei;
    const int* ecol = ei + E;
    const int B  = (n + NPB - 1) / NPB;    // 782 dest buckets
    const int NB = B * T;                  // 3128 bins

    // workspace carve-up (~20.3 MB)
    __half*   hs2    = (__half*)d_ws;                       // n*ND fp16  (6.4 MB)
    unsigned* packed = (unsigned*)(hs2 + (size_t)n * ND);   // E u32      (12.8 MB)
    unsigned* cnt    = packed + (size_t)E;                  // n u32
    unsigned* bincnt = cnt + n;                             // NB u32 (adjacent to cnt for one memset)
    unsigned* boff2  = bincnt + NB;                         // NB u32
    float*    dinv   = (float*)(boff2 + NB);                // n f32
    unsigned* bcur   = (unsigned*)(dinv + n);               // NB*CPAD u32 (200 KB)

    hipMemsetAsync(cnt, 0, ((size_t)n + NB) * sizeof(unsigned), stream);
    k_count2<<<(E + 255) / 256, 256, 0, stream>>>(erow, ecol, E, cnt, bincnt);
    k_dinv<<<(n + 255) / 256, 256, 0, stream>>>(cnt, dinv, n);
    k_scan2<<<1, 1024, 0, stream>>>(bincnt, NB, boff2, bcur);
    k_gemm<<<(n + 255) / 256, 256, 0, stream>>>(x, Wg, dinv, hs2, n);
    k_place<<<(E + EPB - 1) / EPB, 1024, 0, stream>>>(erow, ecol, bcur, packed, E, NB);
    k_agg<<<B, 512, 0, stream>>>(boff2, bincnt, packed, hs2, dinv, bg, Wd, bd, out, n);
}

// Round 6
// 454.619 us; speedup vs baseline: 2.8160x; 2.8160x over previous
//
#include <hip/hip_runtime.h>
#include <hip/hip_fp16.h>

static constexpr int ID   = 128;    // IN_DIM
static constexpr int ND   = 32;     // NET_DIM
static constexpr int NPB  = 64;     // nodes per bucket (lc fits 6 bits)
static constexpr int CPAD = 16;     // u32 per bucket cursor (64B line)
static constexpr int EPB  = 8192;   // edges per k_place block
static constexpr int EPT  = 32;     // edges per thread in k_place
static constexpr int BMAX = 1568;   // >= ceil(100000/64)=1563

union H2U { __half2 h; float f; };
static __device__ __forceinline__ float pack2(float a, float b) {
    H2U z; z.h = __floats2half2_rn(a, b); return z.f;
}

// ---- node in-degree ----
__global__ __launch_bounds__(256) void k_count(const int* __restrict__ col, int E,
                                               unsigned* __restrict__ cnt) {
    int e = blockIdx.x * 256 + threadIdx.x;
    if (e < E) atomicAdd(&cnt[col[e]], 1u);
}

// ---- per-block (256-node) sums of cnt ----
__global__ __launch_bounds__(256) void k_blocksum(const unsigned* __restrict__ cnt, int n,
                                                  unsigned* __restrict__ bsum) {
    __shared__ unsigned s[256];
    int i = blockIdx.x * 256 + threadIdx.x;
    s[threadIdx.x] = (i < n) ? cnt[i] : 0u;
    __syncthreads();
    for (int d = 128; d > 0; d >>= 1) {
        if (threadIdx.x < d) s[threadIdx.x] += s[threadIdx.x + d];
        __syncthreads();
    }
    if (threadIdx.x == 0) bsum[blockIdx.x] = s[0];
}

// ---- exclusive scan of block sums (1 block, nb<=512) ----
__global__ __launch_bounds__(512) void k_scanblocks(const unsigned* __restrict__ bsum, int nb,
                                                    unsigned* __restrict__ boff) {
    __shared__ unsigned s[512];
    int t = threadIdx.x;
    unsigned v0 = (t < nb) ? bsum[t] : 0u;
    s[t] = v0;
    __syncthreads();
    for (int d = 1; d < 512; d <<= 1) {
        unsigned v = (t >= d) ? s[t - d] : 0u;
        __syncthreads();
        s[t] += v;
        __syncthreads();
    }
    if (t < nb) boff[t] = s[t] - v0;   // exclusive
}

// ---- noff = global exclusive scan of cnt; dinv; bucket cursors ----
__global__ __launch_bounds__(256) void k_mkoff(const unsigned* __restrict__ cnt, int n,
                                               const unsigned* __restrict__ boff,
                                               unsigned* __restrict__ noff,
                                               float* __restrict__ dinv,
                                               unsigned* __restrict__ bcur) {
    __shared__ unsigned s[256];
    int i = blockIdx.x * 256 + threadIdx.x;
    unsigned v0 = (i < n) ? cnt[i] : 0u;
    s[threadIdx.x] = v0;
    __syncthreads();
    for (int d = 1; d < 256; d <<= 1) {
        unsigned v = (threadIdx.x >= (unsigned)d) ? s[threadIdx.x - d] : 0u;
        __syncthreads();
        s[threadIdx.x] += v;
        __syncthreads();
    }
    if (i < n) {
        unsigned off = boff[blockIdx.x] + s[threadIdx.x] - v0;   // exclusive
        noff[i] = off;
        dinv[i] = rsqrtf((float)(v0 + 1u));
        if ((i & (NPB - 1)) == 0) bcur[(size_t)(i >> 6) * CPAD] = off;
    }
}

// ---- hs2 = fp16( dinv[i] * (x[i] @ W_gcn) ); float4 W reads ----
__global__ __launch_bounds__(256) void k_gemm(const float* __restrict__ x,
                                              const float* __restrict__ W,
                                              const float* __restrict__ dinv,
                                              __half* __restrict__ hs2, int n) {
    __shared__ float sW[ID * ND];        // 16 KB, [k][j]
    for (int i = threadIdx.x; i < ID * ND; i += 256) sW[i] = W[i];
    __syncthreads();
    int rowi = blockIdx.x * 256 + threadIdx.x;
    if (rowi >= n) return;
    const float4* sW4 = reinterpret_cast<const float4*>(sW);   // [k][8]
    float4 acc4[8];
#pragma unroll
    for (int q = 0; q < 8; ++q) acc4[q] = make_float4(0.f, 0.f, 0.f, 0.f);
    const float4* xr = reinterpret_cast<const float4*>(x + (size_t)rowi * ID);
    for (int k4 = 0; k4 < ID / 4; ++k4) {
        float4 xv = xr[k4];
        float xk[4] = {xv.x, xv.y, xv.z, xv.w};
#pragma unroll
        for (int kk = 0; kk < 4; ++kk) {
            int k = k4 * 4 + kk;
#pragma unroll
            for (int q = 0; q < 8; ++q) {
                float4 w = sW4[k * 8 + q];
                acc4[q].x += xk[kk] * w.x;
                acc4[q].y += xk[kk] * w.y;
                acc4[q].z += xk[kk] * w.z;
                acc4[q].w += xk[kk] * w.w;
            }
        }
    }
    float di = dinv[rowi];
    float4* dst = reinterpret_cast<float4*>(hs2 + (size_t)rowi * ND);
#pragma unroll
    for (int q = 0; q < 4; ++q) {
        float4 f;
        f.x = pack2(di * acc4[2 * q].x,     di * acc4[2 * q].y);
        f.y = pack2(di * acc4[2 * q].z,     di * acc4[2 * q].w);
        f.z = pack2(di * acc4[2 * q + 1].x, di * acc4[2 * q + 1].y);
        f.w = pack2(di * acc4[2 * q + 1].z, di * acc4[2 * q + 1].w);
        dst[q] = f;
    }
}

// ---- two-phase binning into 64-node buckets; per-block chunk reserve ----
__global__ __launch_bounds__(256) void k_place(const int* __restrict__ row,
                                               const int* __restrict__ col,
                                               unsigned* __restrict__ bcur,
                                               unsigned* __restrict__ packed,
                                               int E, int B) {
    __shared__ unsigned lcnt[BMAX];
    __shared__ unsigned lbase[BMAX];
    int tid = threadIdx.x;
    for (int i = tid; i < B; i += 256) lcnt[i] = 0u;
    __syncthreads();
    long base = (long)blockIdx.x * EPB;
    int colv[EPT];
#pragma unroll
    for (int i = 0; i < EPT; ++i) {
        long e = base + tid + (long)i * 256;
        int c = (e < E) ? col[e] : -1;
        colv[i] = c;
        if (c >= 0) atomicAdd(&lcnt[c >> 6], 1u);
    }
    __syncthreads();
    for (int b = tid; b < B; b += 256) {
        unsigned v = lcnt[b];
        lbase[b] = v ? atomicAdd(&bcur[(size_t)b * CPAD], v) : 0u;
        lcnt[b] = 0u;   // reuse as local cursor
    }
    __syncthreads();
#pragma unroll
    for (int i = 0; i < EPT; ++i) {
        long e = base + tid + (long)i * 256;
        if (e < E) {
            int c = colv[i];
            int b = c >> 6;
            unsigned lofs = atomicAdd(&lcnt[b], 1u);
            packed[lbase[b] + lofs] = ((unsigned)(c & (NPB - 1)) << 17) | (unsigned)row[e];
        }
    }
}

// ---- bucket-local counting sort -> node-contiguous srclist ----
__global__ __launch_bounds__(256) void k_bsort(const unsigned* __restrict__ noff,
                                               const unsigned* __restrict__ packed,
                                               unsigned* __restrict__ srclist,
                                               int n, int E) {
    __shared__ unsigned snoff[NPB];
    __shared__ unsigned lcur[NPB];
    int b = blockIdx.x;
    int tid = threadIdx.x;
    if (tid < NPB) {
        int node = b * NPB + tid;
        snoff[tid] = (node < n) ? noff[node] : 0u;
        lcur[tid] = 0u;
    }
    __syncthreads();
    unsigned bstart = snoff[0];
    unsigned bend = (((b + 1) * NPB) < n) ? noff[(b + 1) * NPB] : (unsigned)E;
    for (unsigned i = bstart + (unsigned)tid; i < bend; i += 256u) {
        unsigned u = packed[i];
        unsigned lc = u >> 17;
        unsigned r = u & 0x1FFFFu;
        unsigned lofs = atomicAdd(&lcur[lc], 1u);
        srclist[snoff[lc] + lofs] = r;
    }
}

// ---- gather: one wave per node, register accumulation, fused finalize ----
__global__ __launch_bounds__(256) void k_gather(const unsigned* __restrict__ noff,
                                                const unsigned* __restrict__ cnt,
                                                const unsigned* __restrict__ srclist,
                                                const __half* __restrict__ hs2,
                                                const float* __restrict__ dinv,
                                                const float* __restrict__ bg,
                                                const float* __restrict__ Wd,
                                                const float* __restrict__ bd,
                                                float* __restrict__ out,
                                                int n, int nwaves) {
    int lane = threadIdx.x & 63;
    int wid = (int)((blockIdx.x * 256 + threadIdx.x) >> 6);
    int sub = lane >> 2;       // edge slot 0..15
    int l4  = lane & 3;        // 16B quad of fp16 row (8 channels)
    int ch  = lane & 31;       // dense-phase channel

    // W_dense column in registers: wcol[j] = Wd[j][ch]
    float wcol[32];
#pragma unroll
    for (int j = 0; j < 32; ++j) wcol[j] = Wd[j * 32 + ch];
    float bdv = bd[ch];
    float4 bgA = *reinterpret_cast<const float4*>(bg + l4 * 8);
    float4 bgB = *reinterpret_cast<const float4*>(bg + l4 * 8 + 4);
    float bg8[8] = {bgA.x, bgA.y, bgA.z, bgA.w, bgB.x, bgB.y, bgB.z, bgB.w};

    const float4* hs4 = reinterpret_cast<const float4*>(hs2);   // row = 4 float4

    for (int c = wid; c < n; c += nwaves) {
        unsigned start = noff[c];
        unsigned deg = cnt[c];
        float a[8];
#pragma unroll
        for (int j = 0; j < 8; ++j) a[j] = 0.f;
        for (unsigned k = 0; k < deg; k += 32u) {
            unsigned i0 = k + (unsigned)sub;
            unsigned i1 = k + 16u + (unsigned)sub;
            bool g0 = i0 < deg, g1 = i1 < deg;
            unsigned r0 = g0 ? srclist[start + i0] : 0u;
            unsigned r1 = g1 ? srclist[start + i1] : 0u;
            float4 v0 = hs4[(size_t)r0 * 4 + l4];
            float4 v1 = hs4[(size_t)r1 * 4 + l4];
            if (g0) {
                const __half2* hp = reinterpret_cast<const __half2*>(&v0);
#pragma unroll
                for (int j = 0; j < 4; ++j) {
                    float2 f = __half22float2(hp[j]);
                    a[2 * j] += f.x; a[2 * j + 1] += f.y;
                }
            }
            if (g1) {
                const __half2* hp = reinterpret_cast<const __half2*>(&v1);
#pragma unroll
                for (int j = 0; j < 4; ++j) {
                    float2 f = __half22float2(hp[j]);
                    a[2 * j] += f.x; a[2 * j + 1] += f.y;
                }
            }
        }
        // self-loop term, added once (lanes 0..3 only)
        {
            float4 sv = hs4[(size_t)c * 4 + l4];
            if (sub == 0) {
                const __half2* hp = reinterpret_cast<const __half2*>(&sv);
#pragma unroll
                for (int j = 0; j < 4; ++j) {
                    float2 f = __half22float2(hp[j]);
                    a[2 * j] += f.x; a[2 * j + 1] += f.y;
                }
            }
        }
        // butterfly over sub (lane bits 2..5) -> all lanes hold totals for their l4
#pragma unroll
        for (int st = 4; st <= 32; st <<= 1) {
#pragma unroll
            for (int j = 0; j < 8; ++j) a[j] += __shfl_xor(a[j], st);
        }
        float di = dinv[c];
        float g[8];
#pragma unroll
        for (int j = 0; j < 8; ++j) g[j] = fmaxf(di * a[j] + bg8[j], 0.f);
        // dense: lane needs all 32 g; g[8q+j'] lives in reg g[j'] of lane q (l4==q)
        float o = bdv;
#pragma unroll
        for (int q = 0; q < 4; ++q) {
#pragma unroll
            for (int j = 0; j < 8; ++j) {
                float gj = __shfl(g[j], q);
                o += gj * wcol[q * 8 + j];
            }
        }
        o = fmaxf(o, 0.f);
        if (lane < 32) out[(size_t)c * ND + ch] = o;
    }
}

extern "C" void kernel_launch(void* const* d_in, const int* in_sizes, int n_in,
                              void* d_out, int out_size, void* d_ws, size_t ws_size,
                              hipStream_t stream) {
    const float* x  = (const float*)d_in[0];
    const int*   ei = (const int*)d_in[1];   // [2, E] flat: row then col
    const float* Wg = (const float*)d_in[2];
    const float* bg = (const float*)d_in[3];
    const float* Wd = (const float*)d_in[4];
    const float* bd = (const float*)d_in[5];
    float* out = (float*)d_out;

    const int n = in_sizes[0] / ID;        // 100000
    const int E = in_sizes[1] / 2;         // 3200000
    const int* erow = ei;
    const int* ecol = ei + E;
    const int B  = (n + NPB - 1) / NPB;    // 1563 buckets
    const int nb = (n + 255) / 256;        // 391 scan blocks

    // workspace carve-up (~33.5 MB)
    __half*   hs2     = (__half*)d_ws;                       // n*ND fp16  (6.4 MB)
    unsigned* packed  = (unsigned*)(hs2 + (size_t)n * ND);   // E u32      (12.8 MB)
    unsigned* srclist = packed + (size_t)E;                  // E u32      (12.8 MB)
    unsigned* cnt     = srclist + (size_t)E;                 // n u32
    unsigned* noff    = cnt + n;                             // n u32
    float*    dinv    = (float*)(noff + n);                  // n f32
    unsigned* bsum    = (unsigned*)(dinv + n);               // nb u32
    unsigned* boff    = bsum + nb;                           // nb u32
    unsigned* bcur    = boff + nb;                           // B*CPAD u32 (100 KB)

    hipMemsetAsync(cnt, 0, (size_t)n * sizeof(unsigned), stream);
    k_count<<<(E + 255) / 256, 256, 0, stream>>>(ecol, E, cnt);
    k_blocksum<<<nb, 256, 0, stream>>>(cnt, n, bsum);
    k_scanblocks<<<1, 512, 0, stream>>>(bsum, nb, boff);
    k_mkoff<<<nb, 256, 0, stream>>>(cnt, n, boff, noff, dinv, bcur);
    k_gemm<<<nb, 256, 0, stream>>>(x, Wg, dinv, hs2, n);
    k_place<<<(E + EPB - 1) / EPB, 256, 0, stream>>>(erow, ecol, bcur, packed, E, B);
    k_bsort<<<B, 256, 0, stream>>>(noff, packed, srclist, n, E);
    const int gblocks = 2048;
    k_gather<<<gblocks, 256, 0, stream>>>(noff, cnt, srclist, hs2, dinv,
                                          bg, Wd, bd, out, n, gblocks * 4);
}

// Round 8
// 319.795 us; speedup vs baseline: 4.0032x; 1.4216x over previous
//
#include <hip/hip_runtime.h>
#include <hip/hip_fp16.h>

static constexpr int ID   = 128;    // IN_DIM
static constexpr int ND   = 32;     // NET_DIM
static constexpr int NPB  = 64;     // nodes per bucket (lc fits 6 bits)
static constexpr int CPAD = 16;     // u32 per bucket cursor (64B line)
static constexpr int EPB  = 8192;   // edges per binning block
static constexpr int EPT  = 32;     // edges per thread in k_place
static constexpr int BMAX = 1568;   // >= ceil(100000/64)=1563

union H2U { __half2 h; float f; };
static __device__ __forceinline__ float pack2(float a, float b) {
    H2U z; z.h = __floats2half2_rn(a, b); return z.f;
}

// ---- bucket sizes: LDS-aggregated, one global atomic per (block,bucket) ----
__global__ __launch_bounds__(256) void k_bcnt(const int* __restrict__ col, int E,
                                              unsigned* __restrict__ bsize, int B) {
    __shared__ unsigned lcnt[BMAX];
    int tid = threadIdx.x;
    for (int i = tid; i < B; i += 256) lcnt[i] = 0u;
    __syncthreads();
    long base = (long)blockIdx.x * EPB;
#pragma unroll
    for (int i = 0; i < EPB / 256; ++i) {
        long e = base + tid + (long)i * 256;
        if (e < E) atomicAdd(&lcnt[col[e] >> 6], 1u);
    }
    __syncthreads();
    for (int i = tid; i < B; i += 256) {
        unsigned v = lcnt[i];
        if (v) atomicAdd(&bsize[i], v);
    }
}

// ---- exclusive scan of bucket sizes (1 block, 2/thread, B<=2048) ----
__global__ __launch_bounds__(1024) void k_bscan(const unsigned* __restrict__ bsize, int B,
                                                unsigned* __restrict__ boff,
                                                unsigned* __restrict__ bcur) {
    __shared__ unsigned s[1024];
    int t = threadIdx.x;
    int i0 = 2 * t, i1 = 2 * t + 1;
    unsigned a  = (i0 < B) ? bsize[i0] : 0u;
    unsigned b2 = (i1 < B) ? bsize[i1] : 0u;
    s[t] = a + b2;
    __syncthreads();
    for (int d = 1; d < 1024; d <<= 1) {
        unsigned v = (t >= d) ? s[t - d] : 0u;
        __syncthreads();
        s[t] += v;
        __syncthreads();
    }
    unsigned excl = s[t] - (a + b2);
    if (i0 < B) { boff[i0] = excl;     bcur[(size_t)i0 * CPAD] = excl; }
    if (i1 < B) { boff[i1] = excl + a; bcur[(size_t)i1 * CPAD] = excl + a; }
}

// ---- two-phase binning into 64-node buckets; per-block chunk reserve ----
__global__ __launch_bounds__(256) void k_place(const int* __restrict__ row,
                                               const int* __restrict__ col,
                                               unsigned* __restrict__ bcur,
                                               unsigned* __restrict__ packed,
                                               int E, int B) {
    __shared__ unsigned lcnt[BMAX];
    __shared__ unsigned lbase[BMAX];
    int tid = threadIdx.x;
    for (int i = tid; i < B; i += 256) lcnt[i] = 0u;
    __syncthreads();
    long base = (long)blockIdx.x * EPB;
    int colv[EPT];
#pragma unroll
    for (int i = 0; i < EPT; ++i) {
        long e = base + tid + (long)i * 256;
        int c = (e < E) ? col[e] : -1;
        colv[i] = c;
        if (c >= 0) atomicAdd(&lcnt[c >> 6], 1u);
    }
    __syncthreads();
    for (int b = tid; b < B; b += 256) {
        unsigned v = lcnt[b];
        lbase[b] = v ? atomicAdd(&bcur[(size_t)b * CPAD], v) : 0u;
        lcnt[b] = 0u;   // reuse as local cursor
    }
    __syncthreads();
#pragma unroll
    for (int i = 0; i < EPT; ++i) {
        long e = base + tid + (long)i * 256;
        if (e < E) {
            int c = colv[i];
            int b = c >> 6;
            unsigned lofs = atomicAdd(&lcnt[b], 1u);
            packed[lbase[b] + lofs] = ((unsigned)(c & (NPB - 1)) << 17) | (unsigned)row[e];
        }
    }
}

// ---- bucket-local counting sort; also emits cnt/noff/dinv for its 64 nodes ----
__global__ __launch_bounds__(256) void k_bsort(const unsigned* __restrict__ boff,
                                               const unsigned* __restrict__ bsize,
                                               const unsigned* __restrict__ packed,
                                               unsigned* __restrict__ srclist,
                                               unsigned* __restrict__ cnt,
                                               unsigned* __restrict__ noff,
                                               float* __restrict__ dinv, int n) {
    __shared__ unsigned lcnt[NPB];
    __shared__ unsigned loff[NPB];
    __shared__ unsigned lcur[NPB];
    int b = blockIdx.x;
    int tid = threadIdx.x;
    if (tid < NPB) { lcnt[tid] = 0u; lcur[tid] = 0u; }
    __syncthreads();
    unsigned base = boff[b];
    unsigned m = bsize[b];
    for (unsigned i = (unsigned)tid; i < m; i += 256u)
        atomicAdd(&lcnt[packed[base + i] >> 17], 1u);
    __syncthreads();
    if (tid < NPB) {                         // wave 0: 64-lane inclusive scan
        unsigned v = lcnt[tid];
        unsigned s = v;
#pragma unroll
        for (int d = 1; d < 64; d <<= 1) {
            unsigned t2 = (unsigned)__shfl_up((int)s, d);
            if (tid >= d) s += t2;
        }
        loff[tid] = s - v;                   // exclusive within bucket
        int node = b * NPB + tid;
        if (node < n) {
            cnt[node]  = v;
            noff[node] = base + (s - v);
            dinv[node] = rsqrtf((float)(v + 1u));
        }
    }
    __syncthreads();
    for (unsigned i = (unsigned)tid; i < m; i += 256u) {
        unsigned u = packed[base + i];
        unsigned lc = u >> 17;
        unsigned p = atomicAdd(&lcur[lc], 1u);
        srclist[base + loff[lc] + p] = u & 0x1FFFFu;
    }
}

// ---- hs2 = fp16( dinv[i] * (x[i] @ W_gcn) ); float4 W reads ----
__global__ __launch_bounds__(256) void k_gemm(const float* __restrict__ x,
                                              const float* __restrict__ W,
                                              const float* __restrict__ dinv,
                                              __half* __restrict__ hs2, int n) {
    __shared__ float sW[ID * ND];        // 16 KB, [k][j]
    for (int i = threadIdx.x; i < ID * ND; i += 256) sW[i] = W[i];
    __syncthreads();
    int rowi = blockIdx.x * 256 + threadIdx.x;
    if (rowi >= n) return;
    const float4* sW4 = reinterpret_cast<const float4*>(sW);   // [k][8]
    float4 acc4[8];
#pragma unroll
    for (int q = 0; q < 8; ++q) acc4[q] = make_float4(0.f, 0.f, 0.f, 0.f);
    const float4* xr = reinterpret_cast<const float4*>(x + (size_t)rowi * ID);
    for (int k4 = 0; k4 < ID / 4; ++k4) {
        float4 xv = xr[k4];
        float xk[4] = {xv.x, xv.y, xv.z, xv.w};
#pragma unroll
        for (int kk = 0; kk < 4; ++kk) {
            int k = k4 * 4 + kk;
#pragma unroll
            for (int q = 0; q < 8; ++q) {
                float4 w = sW4[k * 8 + q];
                acc4[q].x += xk[kk] * w.x;
                acc4[q].y += xk[kk] * w.y;
                acc4[q].z += xk[kk] * w.z;
                acc4[q].w += xk[kk] * w.w;
            }
        }
    }
    float di = dinv[rowi];
    float4* dst = reinterpret_cast<float4*>(hs2 + (size_t)rowi * ND);
#pragma unroll
    for (int q = 0; q < 4; ++q) {
        float4 f;
        f.x = pack2(di * acc4[2 * q].x,     di * acc4[2 * q].y);
        f.y = pack2(di * acc4[2 * q].z,     di * acc4[2 * q].w);
        f.z = pack2(di * acc4[2 * q + 1].x, di * acc4[2 * q + 1].y);
        f.w = pack2(di * acc4[2 * q + 1].z, di * acc4[2 * q + 1].w);
        dst[q] = f;
    }
}

// ---- gather: one wave per node, register accumulation, fused finalize ----
__global__ __launch_bounds__(256) void k_gather(const unsigned* __restrict__ noff,
                                                const unsigned* __restrict__ cnt,
                                                const unsigned* __restrict__ srclist,
                                                const __half* __restrict__ hs2,
                                                const float* __restrict__ dinv,
                                                const float* __restrict__ bg,
                                                const float* __restrict__ Wd,
                                                const float* __restrict__ bd,
                                                float* __restrict__ out,
                                                int n, int nwaves) {
    int lane = threadIdx.x & 63;
    int wid = (int)((blockIdx.x * 256 + threadIdx.x) >> 6);
    int sub = lane >> 2;       // edge slot 0..15
    int l4  = lane & 3;        // 16B quad of fp16 row (8 channels)
    int ch  = lane & 31;       // dense-phase channel

    float wcol[32];
#pragma unroll
    for (int j = 0; j < 32; ++j) wcol[j] = Wd[j * 32 + ch];
    float bdv = bd[ch];
    float4 bgA = *reinterpret_cast<const float4*>(bg + l4 * 8);
    float4 bgB = *reinterpret_cast<const float4*>(bg + l4 * 8 + 4);
    float bg8[8] = {bgA.x, bgA.y, bgA.z, bgA.w, bgB.x, bgB.y, bgB.z, bgB.w};

    const float4* hs4 = reinterpret_cast<const float4*>(hs2);   // row = 4 float4

    for (int c = wid; c < n; c += nwaves) {
        unsigned start = noff[c];
        unsigned deg = cnt[c];
        float a[8];
#pragma unroll
        for (int j = 0; j < 8; ++j) a[j] = 0.f;
        for (unsigned k = 0; k < deg; k += 32u) {
            unsigned i0 = k + (unsigned)sub;
            unsigned i1 = k + 16u + (unsigned)sub;
            bool g0 = i0 < deg, g1 = i1 < deg;
            unsigned r0 = g0 ? srclist[start + i0] : 0u;
            unsigned r1 = g1 ? srclist[start + i1] : 0u;
            float4 v0 = hs4[(size_t)r0 * 4 + l4];
            float4 v1 = hs4[(size_t)r1 * 4 + l4];
            if (g0) {
                const __half2* hp = reinterpret_cast<const __half2*>(&v0);
#pragma unroll
                for (int j = 0; j < 4; ++j) {
                    float2 f = __half22float2(hp[j]);
                    a[2 * j] += f.x; a[2 * j + 1] += f.y;
                }
            }
            if (g1) {
                const __half2* hp = reinterpret_cast<const __half2*>(&v1);
#pragma unroll
                for (int j = 0; j < 4; ++j) {
                    float2 f = __half22float2(hp[j]);
                    a[2 * j] += f.x; a[2 * j + 1] += f.y;
                }
            }
        }
        {   // self-loop term, added once (sub==0 lanes only)
            float4 sv = hs4[(size_t)c * 4 + l4];
            if (sub == 0) {
                const __half2* hp = reinterpret_cast<const __half2*>(&sv);
#pragma unroll
                for (int j = 0; j < 4; ++j) {
                    float2 f = __half22float2(hp[j]);
                    a[2 * j] += f.x; a[2 * j + 1] += f.y;
                }
            }
        }
#pragma unroll
        for (int st = 4; st <= 32; st <<= 1) {
#pragma unroll
            for (int j = 0; j < 8; ++j) a[j] += __shfl_xor(a[j], st);
        }
        float di = dinv[c];
        float g[8];
#pragma unroll
        for (int j = 0; j < 8; ++j) g[j] = fmaxf(di * a[j] + bg8[j], 0.f);
        float o = bdv;
#pragma unroll
        for (int q = 0; q < 4; ++q) {
#pragma unroll
            for (int j = 0; j < 8; ++j) {
                float gj = __shfl(g[j], q);
                o += gj * wcol[q * 8 + j];
            }
        }
        o = fmaxf(o, 0.f);
        if (lane < 32) out[(size_t)c * ND + ch] = o;
    }
}

extern "C" void kernel_launch(void* const* d_in, const int* in_sizes, int n_in,
                              void* d_out, int out_size, void* d_ws, size_t ws_size,
                              hipStream_t stream) {
    const float* x  = (const float*)d_in[0];
    const int*   ei = (const int*)d_in[1];   // [2, E] flat: row then col
    const float* Wg = (const float*)d_in[2];
    const float* bg = (const float*)d_in[3];
    const float* Wd = (const float*)d_in[4];
    const float* bd = (const float*)d_in[5];
    float* out = (float*)d_out;

    const int n = in_sizes[0] / ID;        // 100000
    const int E = in_sizes[1] / 2;         // 3200000
    const int* erow = ei;
    const int* ecol = ei + E;
    const int B  = (n + NPB - 1) / NPB;    // 1563 buckets
    const int nb = (n + 255) / 256;        // 391 gemm blocks
    const int ebl = (E + EPB - 1) / EPB;   // 391 binning blocks

    // workspace carve-up (~33 MB)
    __half*   hs2     = (__half*)d_ws;                       // n*ND fp16  (6.4 MB)
    unsigned* packed  = (unsigned*)(hs2 + (size_t)n * ND);   // E u32      (12.8 MB)
    unsigned* srclist = packed + (size_t)E;                  // E u32      (12.8 MB)
    unsigned* cnt     = srclist + (size_t)E;                 // n u32
    unsigned* noff    = cnt + n;                             // n u32
    float*    dinv    = (float*)(noff + n);                  // n f32
    unsigned* bsize   = (unsigned*)(dinv + n);               // B u32
    unsigned* boff    = bsize + B;                           // B u32
    unsigned* bcur    = boff + B;                            // B*CPAD u32 (100 KB)

    hipMemsetAsync(bsize, 0, (size_t)B * sizeof(unsigned), stream);
    k_bcnt<<<ebl, 256, 0, stream>>>(ecol, E, bsize, B);
    k_bscan<<<1, 1024, 0, stream>>>(bsize, B, boff, bcur);
    k_place<<<ebl, 256, 0, stream>>>(erow, ecol, bcur, packed, E, B);
    k_bsort<<<B, 256, 0, stream>>>(boff, bsize, packed, srclist, cnt, noff, dinv, n);
    k_gemm<<<nb, 256, 0, stream>>>(x, Wg, dinv, hs2, n);
    k_gather<<<2048, 256, 0, stream>>>(noff, cnt, srclist, hs2, dinv,
                                       bg, Wd, bd, out, n, 2048 * 4);
}